// Round 1
// baseline (552.157 us; speedup 1.0000x reference)
//
#include <hip/hip_runtime.h>
#include <hip/hip_bf16.h>
#include <math.h>

#define N_SPK 512
#define M_SMP 64
#define D_DIM 768
#define EPS 1e-8f

// ws layout (floats):
// sums   [512*768] @ 0
// ss     [512]     @ 393216
// cn     [512]     @ 393728
// xn     [32768]   @ 394240
// ssame  [32768]   @ 427008
// sdiag  [32768]   @ 459776
// colsum [32768]   @ 492544
// total 525312 floats = 2.1 MB

__global__ __launch_bounds__(256) void kA_sums(const float* __restrict__ x,
    float* __restrict__ sums, float* __restrict__ ss, float* __restrict__ cn) {
  const int n = blockIdx.x;
  const int t = threadIdx.x;
  const float* xp = x + (size_t)n * (M_SMP * D_DIM);
  float lss = 0.f;
#pragma unroll
  for (int q = 0; q < 3; ++q) {
    const int d = t + q * 256;
    float s = 0.f;
    for (int m = 0; m < M_SMP; ++m) s += xp[(size_t)m * D_DIM + d];
    sums[(size_t)n * D_DIM + d] = s;
    lss += s * s;
  }
  for (int o = 32; o; o >>= 1) lss += __shfl_xor(lss, o, 64);
  __shared__ float red[4];
  if ((t & 63) == 0) red[t >> 6] = lss;
  __syncthreads();
  if (t == 0) {
    float v = red[0] + red[1] + red[2] + red[3];
    ss[n] = v;
    cn[n] = fmaxf(sqrtf(v) / (float)M_SMP, EPS);
  }
}

// one wave per row j: xn, S_same (leave-one-out), S_diag (full-centroid value)
__global__ __launch_bounds__(256) void kB_rows(const float* __restrict__ x,
    const float* __restrict__ sums, const float* __restrict__ ss,
    float* __restrict__ xn, float* __restrict__ ssame, float* __restrict__ sdiag,
    const float* __restrict__ wp, const float* __restrict__ bp) {
  const int wave = threadIdx.x >> 6;
  const int lane = threadIdx.x & 63;
  const int j = blockIdx.x * 4 + wave;           // 0..32767
  const int i = j >> 6;                          // speaker
  const float* xp = x + (size_t)j * D_DIM;
  const float* sp = sums + (size_t)i * D_DIM;
  float xx = 0.f, sx = 0.f;
#pragma unroll
  for (int q = 0; q < 3; ++q) {
    const int d = q * 256 + lane * 4;
    float4 xv = *(const float4*)(xp + d);
    float4 sv = *(const float4*)(sp + d);
    xx += xv.x * xv.x + xv.y * xv.y + xv.z * xv.z + xv.w * xv.w;
    sx += sv.x * xv.x + sv.y * xv.y + sv.z * xv.z + sv.w * xv.w;
  }
  for (int o = 32; o; o >>= 1) {
    xx += __shfl_xor(xx, o, 64);
    sx += __shfl_xor(sx, o, 64);
  }
  if (lane == 0) {
    const float w = *wp, b = *bp;
    const float ssi = ss[i];
    const float xnj = fmaxf(sqrtf(xx), EPS);
    const float exn = sqrtf(fmaxf(ssi - 2.f * sx + xx, 0.f)) / (float)(M_SMP - 1);
    const float edot = (sx - xx) / (float)(M_SMP - 1);
    const float s_same = w * edot / (fmaxf(exn, EPS) * xnj) + b;
    const float cni = fmaxf(sqrtf(ssi) / (float)M_SMP, EPS);
    const float s_diag = w * (sx / (float)M_SMP) / (cni * xnj) + b;
    xn[j] = xnj;
    ssame[j] = s_same;
    sdiag[j] = s_diag;
  }
}

// fused GEMM + exp + column-sum. grid (512 j-tiles, 8 n-tiles), 64x64 tile,
// 4x4 microtile per thread, K-step 16.
#define TB 64
#define TK 16
__global__ __launch_bounds__(256) void kC_gemm(const float* __restrict__ x,
    const float* __restrict__ sums, const float* __restrict__ cn,
    const float* __restrict__ xn, float* __restrict__ colsum,
    const float* __restrict__ wp, const float* __restrict__ bp) {
  __shared__ float cT[TK][TB + 1];
  __shared__ float xT[TK][TB + 1];
  __shared__ float csl[TB];
  const int j0 = blockIdx.x * TB;
  const int n0 = blockIdx.y * TB;
  const int t = threadIdx.x;
  const int tx = t & 15;   // j micro index
  const int ty = t >> 4;   // n micro index
  const int lr = t >> 2;        // 0..63 row for staging
  const int lk = (t & 3) * 4;   // 0,4,8,12
  const float invM = 1.0f / (float)M_SMP;
  float acc[4][4] = {};

  for (int k0 = 0; k0 < D_DIM; k0 += TK) {
    float4 cv = *(const float4*)(&sums[(size_t)(n0 + lr) * D_DIM + k0 + lk]);
    float4 xv = *(const float4*)(&x[(size_t)(j0 + lr) * D_DIM + k0 + lk]);
    __syncthreads();
    cT[lk + 0][lr] = cv.x * invM;
    cT[lk + 1][lr] = cv.y * invM;
    cT[lk + 2][lr] = cv.z * invM;
    cT[lk + 3][lr] = cv.w * invM;
    xT[lk + 0][lr] = xv.x;
    xT[lk + 1][lr] = xv.y;
    xT[lk + 2][lr] = xv.z;
    xT[lk + 3][lr] = xv.w;
    __syncthreads();
#pragma unroll
    for (int kk = 0; kk < TK; ++kk) {
      float a0 = cT[kk][ty * 4 + 0];
      float a1 = cT[kk][ty * 4 + 1];
      float a2 = cT[kk][ty * 4 + 2];
      float a3 = cT[kk][ty * 4 + 3];
      float b0 = xT[kk][tx * 4 + 0];
      float b1 = xT[kk][tx * 4 + 1];
      float b2 = xT[kk][tx * 4 + 2];
      float b3 = xT[kk][tx * 4 + 3];
      acc[0][0] += a0 * b0; acc[0][1] += a0 * b1; acc[0][2] += a0 * b2; acc[0][3] += a0 * b3;
      acc[1][0] += a1 * b0; acc[1][1] += a1 * b1; acc[1][2] += a1 * b2; acc[1][3] += a1 * b3;
      acc[2][0] += a2 * b0; acc[2][1] += a2 * b1; acc[2][2] += a2 * b2; acc[2][3] += a2 * b3;
      acc[3][0] += a3 * b0; acc[3][1] += a3 * b1; acc[3][2] += a3 * b2; acc[3][3] += a3 * b3;
    }
  }

  const float w = *wp, b = *bp;
  if (t < TB) csl[t] = 0.f;
  __syncthreads();
  float colp[4] = {0.f, 0.f, 0.f, 0.f};
  float xnv[4];
#pragma unroll
  for (int c = 0; c < 4; ++c) xnv[c] = xn[j0 + tx * 4 + c];
#pragma unroll
  for (int r = 0; r < 4; ++r) {
    const float cni = cn[n0 + ty * 4 + r];
#pragma unroll
    for (int c = 0; c < 4; ++c) {
      const float s = w * acc[r][c] / (cni * xnv[c]) + b;
      colp[c] += __expf(s);
    }
  }
#pragma unroll
  for (int c = 0; c < 4; ++c) atomicAdd(&csl[tx * 4 + c], colp[c]);
  __syncthreads();
  if (t < TB) atomicAdd(&colsum[j0 + t], csl[t]);
}

__global__ __launch_bounds__(256) void kD_final(const float* __restrict__ colsum,
    const float* __restrict__ ssame, const float* __restrict__ sdiag,
    float* __restrict__ out) {
  const int j = blockIdx.x * 256 + threadIdx.x;
  const float sm = ssame[j];
  const float tot = colsum[j] - __expf(sdiag[j]) + __expf(sm);
  float L = -sm + logf(fmaxf(tot, 1e-30f));
  for (int o = 32; o; o >>= 1) L += __shfl_xor(L, o, 64);
  __shared__ float red[4];
  if ((threadIdx.x & 63) == 0) red[threadIdx.x >> 6] = L;
  __syncthreads();
  if (threadIdx.x == 0) atomicAdd(out, red[0] + red[1] + red[2] + red[3]);
}

extern "C" void kernel_launch(void* const* d_in, const int* in_sizes, int n_in,
                              void* d_out, int out_size, void* d_ws, size_t ws_size,
                              hipStream_t stream) {
  const float* x  = (const float*)d_in[0];
  const float* wp = (const float*)d_in[1];
  const float* bp = (const float*)d_in[2];
  float* out = (float*)d_out;
  float* ws = (float*)d_ws;

  float* sums   = ws;
  float* ss     = ws + 393216;
  float* cn     = ws + 393728;
  float* xn     = ws + 394240;
  float* ssame  = ws + 427008;
  float* sdiag  = ws + 459776;
  float* colsum = ws + 492544;

  hipMemsetAsync(colsum, 0, 32768 * sizeof(float), stream);
  hipMemsetAsync(out, 0, sizeof(float), stream);

  kA_sums<<<512, 256, 0, stream>>>(x, sums, ss, cn);
  kB_rows<<<8192, 256, 0, stream>>>(x, sums, ss, xn, ssame, sdiag, wp, bp);
  dim3 gC(512, 8);
  kC_gemm<<<gC, 256, 0, stream>>>(x, sums, cn, xn, colsum, wp, bp);
  kD_final<<<128, 256, 0, stream>>>(colsum, ssame, sdiag, out);
}

// Round 2
// 109.868 us; speedup vs baseline: 5.0256x; 5.0256x over previous
//
#include <hip/hip_runtime.h>
#include <hip/hip_bf16.h>
#include <math.h>

#define N_SPK 512
#define M_SMP 64
#define D_DIM 768
#define EPS 1e-8f

typedef __attribute__((ext_vector_type(8))) short short8;
typedef __attribute__((ext_vector_type(4))) float floatx4;

// ws layout (floats):
// sums    [512*768]  @ 0
// ss      [512]      @ 393216
// rcn     [512]      @ 393728
// rxn     [32768]    @ 394240
// ssame   [32768]    @ 427008
// sdiag   [32768]    @ 459776
// colsum  [32768]    @ 492544
// sums_bf [512*768]u @ 525312 (as ushort; 196608 floats)
// total 721920 floats = 2.89 MB

__device__ __forceinline__ unsigned short f2bf(float f) {
  unsigned int u = __float_as_uint(f);
  u += 0x7FFFu + ((u >> 16) & 1u);   // round-to-nearest-even
  return (unsigned short)(u >> 16);
}

__global__ __launch_bounds__(256) void kA_sums(const float* __restrict__ x,
    float* __restrict__ sums, unsigned short* __restrict__ sums_bf,
    float* __restrict__ ss, float* __restrict__ rcn, const float* __restrict__ wp) {
  const int n = blockIdx.x;
  const int t = threadIdx.x;
  const float* xp = x + (size_t)n * (M_SMP * D_DIM);
  float lss = 0.f;
#pragma unroll
  for (int q = 0; q < 3; ++q) {
    const int d = t + q * 256;
    float s = 0.f;
    for (int m = 0; m < M_SMP; ++m) s += xp[(size_t)m * D_DIM + d];
    sums[(size_t)n * D_DIM + d] = s;
    sums_bf[(size_t)n * D_DIM + d] = f2bf(s);
    lss += s * s;
  }
  for (int o = 32; o; o >>= 1) lss += __shfl_xor(lss, o, 64);
  __shared__ float red[4];
  if ((t & 63) == 0) red[t >> 6] = lss;
  __syncthreads();
  if (t == 0) {
    const float v = red[0] + red[1] + red[2] + red[3];
    ss[n] = v;
    const float cni = fmaxf(sqrtf(v) / (float)M_SMP, EPS);
    rcn[n] = (*wp) / ((float)M_SMP * cni);   // S = acc * rcn[n] * rxn[j] + b
  }
}

// one wave per row j: rxn, S_same (leave-one-out), S_diag
__global__ __launch_bounds__(256) void kB_rows(const float* __restrict__ x,
    const float* __restrict__ sums, const float* __restrict__ ss,
    float* __restrict__ rxn, float* __restrict__ ssame, float* __restrict__ sdiag,
    const float* __restrict__ wp, const float* __restrict__ bp) {
  const int wave = threadIdx.x >> 6;
  const int lane = threadIdx.x & 63;
  const int j = blockIdx.x * 4 + wave;           // 0..32767
  const int i = j >> 6;                          // speaker
  const float* xp = x + (size_t)j * D_DIM;
  const float* sp = sums + (size_t)i * D_DIM;
  float xx = 0.f, sx = 0.f;
#pragma unroll
  for (int q = 0; q < 3; ++q) {
    const int d = q * 256 + lane * 4;
    float4 xv = *(const float4*)(xp + d);
    float4 sv = *(const float4*)(sp + d);
    xx += xv.x * xv.x + xv.y * xv.y + xv.z * xv.z + xv.w * xv.w;
    sx += sv.x * xv.x + sv.y * xv.y + sv.z * xv.z + sv.w * xv.w;
  }
  for (int o = 32; o; o >>= 1) {
    xx += __shfl_xor(xx, o, 64);
    sx += __shfl_xor(sx, o, 64);
  }
  if (lane == 0) {
    const float w = *wp, b = *bp;
    const float ssi = ss[i];
    const float xnj = fmaxf(sqrtf(xx), EPS);
    const float exn = sqrtf(fmaxf(ssi - 2.f * sx + xx, 0.f)) / (float)(M_SMP - 1);
    const float edot = (sx - xx) / (float)(M_SMP - 1);
    const float s_same = w * edot / (fmaxf(exn, EPS) * xnj) + b;
    const float cni = fmaxf(sqrtf(ssi) / (float)M_SMP, EPS);
    const float s_diag = w * (sx / (float)M_SMP) / (cni * xnj) + b;
    rxn[j] = 1.0f / xnj;
    ssame[j] = s_same;
    sdiag[j] = s_diag;
  }
}

// MFMA GEMM: block = 64 j-cols x all 512 n. 4 waves x 16 j each.
// B (x rows) in regs (bf16, converted on the fly), full K=768 = 24 frags.
// A (sums_bf) staged 16n x 768k per tile, double-buffered LDS, XOR-swizzled.
__global__ __launch_bounds__(256) void kC_mfma(const float* __restrict__ x,
    const unsigned short* __restrict__ sums_bf,
    const float* __restrict__ rcn, const float* __restrict__ rxn,
    float* __restrict__ colsum, const float* __restrict__ bp) {
  __shared__ unsigned short As[2][16 * D_DIM];   // 2 x 24 KB
  const int t = threadIdx.x;
  const int w = t >> 6;
  const int l = t & 63;
  const int lr = l & 15;          // frag row (A: n-row, B: j-col)
  const int lg = l >> 4;          // frag k-group 0..3
  const int jw = blockIdx.x * 64 + w * 16;       // wave's j base

  // ---- B fragments: x[jw+lr][kk*32 + lg*8 .. +8], fp32 -> bf16
  short8 bfr[24];
  {
    const float* xrow = x + (size_t)(jw + lr) * D_DIM;
#pragma unroll
    for (int kk = 0; kk < 24; ++kk) {
      const float* p = xrow + kk * 32 + lg * 8;
      float4 u0 = *(const float4*)(p);
      float4 u1 = *(const float4*)(p + 4);
      short8 r;
      r[0] = (short)f2bf(u0.x); r[1] = (short)f2bf(u0.y);
      r[2] = (short)f2bf(u0.z); r[3] = (short)f2bf(u0.w);
      r[4] = (short)f2bf(u1.x); r[5] = (short)f2bf(u1.y);
      r[6] = (short)f2bf(u1.z); r[7] = (short)f2bf(u1.w);
      bfr[kk] = r;
    }
  }
  const float rx = rxn[jw + lr];
  const float b = *bp;
  float colp = 0.f;

  // staging mapping: thread t stages row srow, chunks (sc16 + 16q), q=0..5
  const int srow = t >> 4;        // 0..15
  const int sc16 = t & 15;
  const int swz = (srow & 7) << 4;

  // prologue: stage tile 0
  {
    const unsigned short* gp = sums_bf + (size_t)srow * D_DIM;
    unsigned short* As0 = As[0];
#pragma unroll
    for (int q = 0; q < 6; ++q) {
      const int c = sc16 + 16 * q;
      uint4 v = *(const uint4*)(gp + c * 8);
      *(uint4*)((char*)As0 + srow * 1536 + ((c * 16) ^ swz)) = v;
    }
  }
  __syncthreads();

  const int rswz = (lr & 7) << 4;
  for (int nt = 0; nt < 32; ++nt) {
    const int n0 = nt * 16;
    // issue next tile's global loads early
    uint4 nxt[6];
    if (nt < 31) {
      const unsigned short* gp = sums_bf + (size_t)(n0 + 16 + srow) * D_DIM;
#pragma unroll
      for (int q = 0; q < 6; ++q) nxt[q] = *(const uint4*)(gp + (sc16 + 16 * q) * 8);
    }
    // MFMA over K=768
    floatx4 acc = {0.f, 0.f, 0.f, 0.f};
    const char* Ab = (const char*)As[nt & 1];
#pragma unroll
    for (int kk = 0; kk < 24; ++kk) {
      short8 afr = *(const short8*)(Ab + lr * 1536 + ((kk * 64 + lg * 16) ^ rswz));
      acc = __builtin_amdgcn_mfma_f32_16x16x32_bf16(afr, bfr[kk], acc, 0, 0, 0);
    }
    // epilogue: S = acc * rcn[n] * rxn[j] + b ; colp += exp(S)
    {
      float4 rc = *(const float4*)&rcn[n0 + lg * 4];
      colp += __expf(acc[0] * rc.x * rx + b);
      colp += __expf(acc[1] * rc.y * rx + b);
      colp += __expf(acc[2] * rc.z * rx + b);
      colp += __expf(acc[3] * rc.w * rx + b);
    }
    // write staged regs to the other buffer
    if (nt < 31) {
      char* Aw = (char*)As[(nt + 1) & 1];
#pragma unroll
      for (int q = 0; q < 6; ++q) {
        const int c = sc16 + 16 * q;
        *(uint4*)(Aw + srow * 1536 + ((c * 16) ^ swz)) = nxt[q];
      }
      __syncthreads();
    }
  }

  // reduce colp across the 4 k-groups (lanes l, l^16, l^32, l^48 share a col)
  colp += __shfl_xor(colp, 16, 64);
  colp += __shfl_xor(colp, 32, 64);
  if (l < 16) colsum[jw + l] = colp;
}

__global__ __launch_bounds__(256) void kD_final(const float* __restrict__ colsum,
    const float* __restrict__ ssame, const float* __restrict__ sdiag,
    float* __restrict__ out) {
  const int j = blockIdx.x * 256 + threadIdx.x;
  const float sm = ssame[j];
  const float tot = colsum[j] - __expf(sdiag[j]) + __expf(sm);
  float L = -sm + logf(fmaxf(tot, 1e-30f));
  for (int o = 32; o; o >>= 1) L += __shfl_xor(L, o, 64);
  __shared__ float red[4];
  if ((threadIdx.x & 63) == 0) red[threadIdx.x >> 6] = L;
  __syncthreads();
  if (threadIdx.x == 0) atomicAdd(out, red[0] + red[1] + red[2] + red[3]);
}

extern "C" void kernel_launch(void* const* d_in, const int* in_sizes, int n_in,
                              void* d_out, int out_size, void* d_ws, size_t ws_size,
                              hipStream_t stream) {
  const float* x  = (const float*)d_in[0];
  const float* wp = (const float*)d_in[1];
  const float* bp = (const float*)d_in[2];
  float* out = (float*)d_out;
  float* ws = (float*)d_ws;

  float* sums   = ws;
  float* ss     = ws + 393216;
  float* rcn    = ws + 393728;
  float* rxn    = ws + 394240;
  float* ssame  = ws + 427008;
  float* sdiag  = ws + 459776;
  float* colsum = ws + 492544;
  unsigned short* sums_bf = (unsigned short*)(ws + 525312);

  hipMemsetAsync(out, 0, sizeof(float), stream);

  kA_sums<<<512, 256, 0, stream>>>(x, sums, sums_bf, ss, rcn, wp);
  kB_rows<<<8192, 256, 0, stream>>>(x, sums, ss, rxn, ssame, sdiag, wp, bp);
  kC_mfma<<<512, 256, 0, stream>>>(x, sums_bf, rcn, rxn, colsum, bp);
  kD_final<<<128, 256, 0, stream>>>(colsum, ssame, sdiag, out);
}